// Round 1
// baseline (109.455 us; speedup 1.0000x reference)
//
#include <hip/hip_runtime.h>

// Hawkes point-process log-likelihood, N=16 sequences, T=2048 events.
// out[n] = sum_i m_i*[log(alpha*S_i + mu + 1e-8) + (alpha/beta)*(exp(-beta*(t1-t_i)) - 1)]
//          - (t1-t0)*mu,   where S_i = sum_{j<i} exp(-beta*(t_i - t_j)).
// Direct exp-sum replaces the reference's logsumexp (all args <= 0 -> safe).

#define NSEQ 16
#define TLEN 2048
#define CHUNKS 16                      // blocks per sequence
#define ROWS_PER_BLOCK (TLEN / CHUNKS) // 128 rows per block, strided by CHUNKS

__device__ __forceinline__ float softplus_f(float x) {
    // stable log(1+exp(x))
    return fmaxf(x, 0.0f) + log1pf(__expf(-fabsf(x)));
}

__global__ void zero_out_kernel(float* __restrict__ out, int nel) {
    int i = blockIdx.x * blockDim.x + threadIdx.x;
    if (i < nel) out[i] = 0.0f;
}

__global__ __launch_bounds__(256) void hawkes_kernel(
    const float* __restrict__ et,   // (N,T) sorted event times
    const float* __restrict__ mask, // (N,T)
    const float* __restrict__ t0,   // (N,)
    const float* __restrict__ t1,   // (N,)
    const float* __restrict__ mu_p, // (1,)
    const float* __restrict__ al_p, // (1,)
    const float* __restrict__ be_p, // (1,)
    float* __restrict__ out)        // (N,)
{
    __shared__ float s_et[TLEN];
    __shared__ float s_wacc[4];

    const int n     = blockIdx.x / CHUNKS;
    const int chunk = blockIdx.x % CHUNKS;

    const float* etn = et + n * TLEN;
    for (int j = threadIdx.x; j < TLEN; j += 256) s_et[j] = etn[j];
    __syncthreads();

    const float mu_ = softplus_f(mu_p[0]);
    const float al_ = softplus_f(al_p[0]);
    const float be_ = softplus_f(be_p[0]);
    const float ab  = al_ / be_;
    const float t1n = t1[n];

    const int wave = threadIdx.x >> 6;
    const int lane = threadIdx.x & 63;

    float acc = 0.0f;
    // rows i = chunk + CHUNKS*r : uniform spread of triangle lengths -> balanced
    for (int r = wave; r < ROWS_PER_BLOCK; r += 4) {
        const int i = chunk + CHUNKS * r;
        const float ti = s_et[i];
        float s = 0.0f;
        for (int j = lane; j < i; j += 64)
            s += __expf(be_ * (s_et[j] - ti));   // exp(-beta*(ti - tj)), arg <= 0
        #pragma unroll
        for (int off = 32; off > 0; off >>= 1)
            s += __shfl_down(s, off);
        if (lane == 0) {
            const float m    = mask[n * TLEN + i];
            const float lamb = al_ * s + mu_;
            acc += m * (__logf(lamb + 1e-8f)
                        + ab * (__expf(be_ * (ti - t1n)) - 1.0f));
        }
    }

    if (lane == 0) s_wacc[wave] = acc;
    __syncthreads();
    if (threadIdx.x == 0) {
        float tot = s_wacc[0] + s_wacc[1] + s_wacc[2] + s_wacc[3];
        if (chunk == 0) tot -= (t1n - t0[n]) * mu_;  // per-sequence constant once
        atomicAdd(&out[n], tot);
    }
}

extern "C" void kernel_launch(void* const* d_in, const int* in_sizes, int n_in,
                              void* d_out, int out_size, void* d_ws, size_t ws_size,
                              hipStream_t stream) {
    const float* et   = (const float*)d_in[0];
    const float* mask = (const float*)d_in[1];
    const float* t0   = (const float*)d_in[2];
    const float* t1   = (const float*)d_in[3];
    const float* mu_p = (const float*)d_in[4];
    const float* al_p = (const float*)d_in[5];
    const float* be_p = (const float*)d_in[6];
    float* out = (float*)d_out;

    zero_out_kernel<<<1, 64, 0, stream>>>(out, out_size);
    hawkes_kernel<<<NSEQ * CHUNKS, 256, 0, stream>>>(et, mask, t0, t1,
                                                     mu_p, al_p, be_p, out);
}

// Round 3
// 67.856 us; speedup vs baseline: 1.6130x; 1.6130x over previous
//
#include <hip/hip_runtime.h>

// Hawkes log-likelihood via the O(T) recurrence S_i = exp(-beta*(t_i-t_{i-1}))*(S_{i-1}+1),
// parallelized with an affine-composition scan (A,B): s -> A*s + B.
// One block per sequence (N=16), 256 threads, 8 consecutive elements per thread.
// out[n] = sum_i m_i*[log(alpha*S_i+mu+1e-8) + (alpha/beta)*(exp(beta*(t_i-t1)) - 1)] - (t1-t0)*mu

#define NSEQ 16
#define TLEN 2048
#define EPT 8          // elements per thread (256*8 = 2048)

__device__ __forceinline__ float softplus_f(float x) {
    return fmaxf(x, 0.0f) + log1pf(__expf(-fabsf(x)));
}

__global__ __launch_bounds__(256) void hawkes_scan_kernel(
    const float* __restrict__ et,   // (N,T) sorted event times
    const float* __restrict__ mask, // (N,T)
    const float* __restrict__ t0,   // (N,)
    const float* __restrict__ t1,   // (N,)
    const float* __restrict__ mu_p,
    const float* __restrict__ al_p,
    const float* __restrict__ be_p,
    float* __restrict__ out)        // (N,)
{
    __shared__ float  s_last[4];    // last t of each wave (for chunk-boundary t_prev)
    __shared__ float2 s_agg[4];     // per-wave scan aggregates (A,B) in (.x,.y)
    __shared__ float  s_red[4];     // final reduction

    const int n    = blockIdx.x;
    const int tid  = threadIdx.x;
    const int wave = tid >> 6;
    const int lane = tid & 63;
    const int base = tid * EPT;     // first global element index for this thread

    const float mu_ = softplus_f(mu_p[0]);
    const float al_ = softplus_f(al_p[0]);
    const float be_ = softplus_f(be_p[0]);
    const float ab  = al_ / be_;
    const float t1n = t1[n];

    // ---- load 8 events + 8 masks (coalesced float4) ----
    const float4* etv = reinterpret_cast<const float4*>(et + n * TLEN + base);
    const float4* mkv = reinterpret_cast<const float4*>(mask + n * TLEN + base);
    float4 e0 = etv[0], e1 = etv[1];
    float4 m0 = mkv[0], m1 = mkv[1];
    float t[EPT] = {e0.x, e0.y, e0.z, e0.w, e1.x, e1.y, e1.z, e1.w};
    float m[EPT] = {m0.x, m0.y, m0.z, m0.w, m1.x, m1.y, m1.z, m1.w};

    // ---- t_prev for element base (last element of previous thread) ----
    if (lane == 63) s_last[wave] = t[EPT - 1];
    __syncthreads();
    float tprev = __shfl_up(t[EPT - 1], 1);
    if (lane == 0 && wave > 0) tprev = s_last[wave - 1];

    // ---- per-element decay factors a_i = exp(-beta*(t_i - t_{i-1})) ----
    float a[EPT];
    a[0] = (base == 0) ? 0.0f : __expf(be_ * (tprev - t[0]));
    #pragma unroll
    for (int k = 1; k < EPT; ++k) a[k] = __expf(be_ * (t[k - 1] - t[k]));

    // ---- local affine compose: state s -> A*s + B over this thread's 8 steps ----
    float A, B;
    if (base == 0) { A = 0.0f; B = 0.0f; }           // f_0 forces S_0 = 0
    else           { A = a[0]; B = a[0]; }           // f: s -> a*(s+1)
    #pragma unroll
    for (int k = 1; k < EPT; ++k) { B = a[k] * (B + 1.0f); A = a[k] * A; }

    // ---- inclusive wave scan of (A,B) under composition ----
    #pragma unroll
    for (int off = 1; off < 64; off <<= 1) {
        float pA = __shfl_up(A, off);
        float pB = __shfl_up(B, off);
        if (lane >= off) { B = A * pB + B; A = A * pA; }
    }

    // exclusive within-wave prefix
    float eA = __shfl_up(A, 1), eB = __shfl_up(B, 1);
    if (lane == 0) { eA = 1.0f; eB = 0.0f; }

    // wave aggregates -> cross-wave exclusive prefix
    if (lane == 63) s_agg[wave] = make_float2(A, B);
    __syncthreads();
    float wpA = 1.0f, wpB = 0.0f;
    for (int w = 0; w < wave; ++w) {
        float2 g = s_agg[w];          // g.x = A_w, g.y = B_w
        wpB = g.x * wpB + g.y;        // compose: wp then g
        wpA = g.x * wpA;
    }

    // incoming state for this thread's chunk: apply wp, then within-wave exclusive
    float S = eA * wpB + eB;     // S_{base-1}  (initial global state = 0)

    // ---- replay: per-element intensity + compensator contribution ----
    float acc = 0.0f;
    #pragma unroll
    for (int k = 0; k < EPT; ++k) {
        if (base + k == 0) S = 0.0f;
        else               S = a[k] * (S + 1.0f);
        const float lamb = al_ * S + mu_;
        acc += m[k] * (__logf(lamb + 1e-8f)
                       + ab * (__expf(be_ * (t[k] - t1n)) - 1.0f));
    }

    // ---- block reduction ----
    #pragma unroll
    for (int off = 32; off > 0; off >>= 1) acc += __shfl_down(acc, off);
    if (lane == 0) s_red[wave] = acc;
    __syncthreads();
    if (tid == 0) {
        float tot = s_red[0] + s_red[1] + s_red[2] + s_red[3];
        out[n] = tot - (t1n - t0[n]) * mu_;
    }
}

extern "C" void kernel_launch(void* const* d_in, const int* in_sizes, int n_in,
                              void* d_out, int out_size, void* d_ws, size_t ws_size,
                              hipStream_t stream) {
    const float* et   = (const float*)d_in[0];
    const float* mask = (const float*)d_in[1];
    const float* t0   = (const float*)d_in[2];
    const float* t1   = (const float*)d_in[3];
    const float* mu_p = (const float*)d_in[4];
    const float* al_p = (const float*)d_in[5];
    const float* be_p = (const float*)d_in[6];
    float* out = (float*)d_out;

    hawkes_scan_kernel<<<NSEQ, 256, 0, stream>>>(et, mask, t0, t1,
                                                 mu_p, al_p, be_p, out);
}